// Round 1
// baseline (2519.402 us; speedup 1.0000x reference)
//
#include <hip/hip_runtime.h>

#define N_NODES 10000
#define N_EDGES 320000
#define NE_TOT  330000   /* E + N */
#define NEG_SLOPE 0.2f
#define LN_EPS 1e-5f

/* workspace layout (bytes) */
#define OFF_CNT    0u         /* int[N]            */
#define OFF_FILL   40000u     /* int[N]            */
#define OFF_ROWPTR 80128u     /* int[N+1]          */
#define OFF_EIDS   120320u    /* int[E+N]          */
#define OFF_LATTR  1440512u   /* float[N*64]       */
#define OFF_XL     4000512u   /* float[N*256]      */
#define OFF_XR     14240512u  /* float[N*256]      */
#define OFF_LOG    24480512u  /* float[(E+N)*4]    */

__global__ void k_count(const int* __restrict__ ei, int* __restrict__ cnt) {
    int e = blockIdx.x * blockDim.x + threadIdx.x;
    if (e < N_EDGES) atomicAdd(&cnt[ei[N_EDGES + e]], 1);
}

__global__ void k_scan(const int* __restrict__ cnt, int* __restrict__ row_ptr) {
    __shared__ int sums[256];
    int t = threadIdx.x;
    const int CH = (N_NODES + 255) / 256;   /* 40 */
    int base = t * CH;
    int s = 0;
    for (int i = 0; i < CH; i++) {
        int n = base + i;
        if (n < N_NODES) s += cnt[n] + 1;   /* +1 self loop */
    }
    sums[t] = s;
    __syncthreads();
    for (int off = 1; off < 256; off <<= 1) {
        int v = (t >= off) ? sums[t - off] : 0;
        __syncthreads();
        sums[t] += v;
        __syncthreads();
    }
    int run = (t == 0) ? 0 : sums[t - 1];
    for (int i = 0; i < CH; i++) {
        int n = base + i;
        if (n < N_NODES) { row_ptr[n] = run; run += cnt[n] + 1; }
    }
    if (t == 255) row_ptr[N_NODES] = sums[255];
}

__global__ void k_fill(const int* __restrict__ ei, const int* __restrict__ row_ptr,
                       int* __restrict__ fill, int* __restrict__ eids) {
    int e = blockIdx.x * blockDim.x + threadIdx.x;
    if (e >= NE_TOT) return;
    int d = (e < N_EDGES) ? ei[N_EDGES + e] : (e - N_EDGES);
    int pos = atomicAdd(&fill[d], 1);
    eids[row_ptr[d] + pos] = e;
}

/* one wave per node: mean of incoming edge_attr (original edges only) */
__global__ void k_loop_attr(const float* __restrict__ edge_attr,
                            const int* __restrict__ row_ptr,
                            const int* __restrict__ eids,
                            const int* __restrict__ cnt,
                            float* __restrict__ lattr) {
    int node = (blockIdx.x << 2) + (threadIdx.x >> 6);
    int lane = threadIdx.x & 63;
    int b = row_ptr[node], en = row_ptr[node + 1];
    float s = 0.0f;
    for (int i = b; i < en; i++) {
        int e = eids[i];
        if (e < N_EDGES) s += edge_attr[e * 64 + lane];
    }
    float c = (float)cnt[node];
    lattr[node * 64 + lane] = s / fmaxf(c, 1.0f);
}

/* xl = x@Wl^T + bl ; xr = x@Wr^T + br.  8 nodes per 256-thread block. */
__global__ void k_gemm_xlxr(const float* __restrict__ x,
                            const float* __restrict__ Wl, const float* __restrict__ bl,
                            const float* __restrict__ Wr, const float* __restrict__ br,
                            float* __restrict__ xl, float* __restrict__ xr) {
    __shared__ float xs[8][256];
    int t = threadIdx.x;
    int nb = blockIdx.x * 8;
#pragma unroll
    for (int nn = 0; nn < 8; nn++) xs[nn][t] = x[(nb + nn) * 256 + t];
    __syncthreads();

    float accl[8], accr[8];
    float b0 = bl[t], b1 = br[t];
#pragma unroll
    for (int nn = 0; nn < 8; nn++) { accl[nn] = b0; accr[nn] = b1; }

    const float4* wl4 = reinterpret_cast<const float4*>(Wl) + t * 64;
    const float4* wr4 = reinterpret_cast<const float4*>(Wr) + t * 64;
    for (int i = 0; i < 64; i++) {
        float4 wl = wl4[i];
        float4 wr = wr4[i];
#pragma unroll
        for (int nn = 0; nn < 8; nn++) {
            float4 xv = reinterpret_cast<const float4*>(xs[nn])[i];
            accl[nn] = fmaf(xv.x, wl.x, accl[nn]);
            accl[nn] = fmaf(xv.y, wl.y, accl[nn]);
            accl[nn] = fmaf(xv.z, wl.z, accl[nn]);
            accl[nn] = fmaf(xv.w, wl.w, accl[nn]);
            accr[nn] = fmaf(xv.x, wr.x, accr[nn]);
            accr[nn] = fmaf(xv.y, wr.y, accr[nn]);
            accr[nn] = fmaf(xv.z, wr.z, accr[nn]);
            accr[nn] = fmaf(xv.w, wr.w, accr[nn]);
        }
    }
#pragma unroll
    for (int nn = 0; nn < 8; nn++) {
        xl[(nb + nn) * 256 + t] = accl[nn];
        xr[(nb + nn) * 256 + t] = accr[nn];
    }
}

/* logits[e][h] = sum_c lrelu(xl[src]+xr[dst]+ea@We^T)[h,c] * att[h,c]
   one wave per edge, We^T staged in 64KB LDS as [k][d]. */
__global__ void k_logits(const int* __restrict__ ei,
                         const float* __restrict__ edge_attr,
                         const float* __restrict__ lattr,
                         const float* __restrict__ xl, const float* __restrict__ xr,
                         const float* __restrict__ We, const float* __restrict__ att,
                         float* __restrict__ logits) {
    __shared__ float WeT[16384];   /* [k=64][d=256], 64 KB */
    int tid = threadIdx.x;
    for (int a = tid; a < 16384; a += 1024) {
        /* WeT[k*256+d] = We[d*64+k]; identity: a = k*256+d */
        WeT[a] = We[((a & 255) << 6) + (a >> 8)];
    }
    __syncthreads();

    int lane = tid & 63;
    int wid = (blockIdx.x << 4) + (tid >> 6);
    int nw = (gridDim.x << 4);
    const float4 att4 = reinterpret_cast<const float4*>(att)[lane];
    const float4* xl4p = reinterpret_cast<const float4*>(xl);
    const float4* xr4p = reinterpret_cast<const float4*>(xr);

    for (int e = wid; e < NE_TOT; e += nw) {
        int s, d;
        float ea;
        if (e < N_EDGES) {
            s = ei[e];
            d = ei[N_EDGES + e];
            ea = edge_attr[e * 64 + lane];
        } else {
            s = e - N_EDGES;
            d = s;
            ea = lattr[s * 64 + lane];
        }
        float4 av = xl4p[s * 64 + lane];
        float4 bv = xr4p[d * 64 + lane];
        float4 acc;
        acc.x = av.x + bv.x; acc.y = av.y + bv.y;
        acc.z = av.z + bv.z; acc.w = av.w + bv.w;
#pragma unroll
        for (int k = 0; k < 64; k++) {
            float a = __shfl(ea, k, 64);
            float4 w = *reinterpret_cast<const float4*>(&WeT[(k << 8) + (lane << 2)]);
            acc.x = fmaf(a, w.x, acc.x);
            acc.y = fmaf(a, w.y, acc.y);
            acc.z = fmaf(a, w.z, acc.z);
            acc.w = fmaf(a, w.w, acc.w);
        }
        float mx0 = acc.x >= 0.0f ? acc.x : NEG_SLOPE * acc.x;
        float mx1 = acc.y >= 0.0f ? acc.y : NEG_SLOPE * acc.y;
        float mx2 = acc.z >= 0.0f ? acc.z : NEG_SLOPE * acc.z;
        float mx3 = acc.w >= 0.0f ? acc.w : NEG_SLOPE * acc.w;
        float v = mx0 * att4.x + mx1 * att4.y + mx2 * att4.z + mx3 * att4.w;
        v += __shfl_xor(v, 1, 64);
        v += __shfl_xor(v, 2, 64);
        v += __shfl_xor(v, 4, 64);
        v += __shfl_xor(v, 8, 64);
        if ((lane & 15) == 0) logits[e * 4 + (lane >> 4)] = v;
    }
}

/* one wave per node: segment softmax + weighted sum + bias + SiLU + LayerNorm */
__global__ void k_aggregate(const int* __restrict__ ei,
                            const int* __restrict__ row_ptr,
                            const int* __restrict__ eids,
                            const float* __restrict__ logits,
                            const float* __restrict__ xl,
                            const float* __restrict__ bias,
                            const float* __restrict__ gamma,
                            const float* __restrict__ beta,
                            float* __restrict__ hout,
                            float* __restrict__ alpha_out) {
    int node = (blockIdx.x << 2) + (threadIdx.x >> 6);
    int lane = threadIdx.x & 63;
    int h = lane >> 4;
    int b = row_ptr[node], en = row_ptr[node + 1];

    float mh = -INFINITY;
    for (int i = b; i < en; i++) {
        int e = eids[i];
        mh = fmaxf(mh, logits[e * 4 + h]);
    }
    float den = 0.0f;
    for (int i = b; i < en; i++) {
        int e = eids[i];
        den += __expf(logits[e * 4 + h] - mh);
    }
    float rden = 1.0f / den;

    const float4* xl4p = reinterpret_cast<const float4*>(xl);
    float4 acc; acc.x = acc.y = acc.z = acc.w = 0.0f;
    for (int i = b; i < en; i++) {
        int e = eids[i];
        float al = __expf(logits[e * 4 + h] - mh) * rden;
        if ((lane & 15) == 0) alpha_out[e * 4 + h] = al;
        int s = (e < N_EDGES) ? ei[e] : (e - N_EDGES);
        float4 xv = xl4p[s * 64 + lane];
        acc.x = fmaf(al, xv.x, acc.x);
        acc.y = fmaf(al, xv.y, acc.y);
        acc.z = fmaf(al, xv.z, acc.z);
        acc.w = fmaf(al, xv.w, acc.w);
    }

    const float4 b4 = reinterpret_cast<const float4*>(bias)[lane];
    float4 hv;
    hv.x = acc.x + b4.x; hv.y = acc.y + b4.y;
    hv.z = acc.z + b4.z; hv.w = acc.w + b4.w;
    /* SiLU */
    hv.x = hv.x / (1.0f + __expf(-hv.x));
    hv.y = hv.y / (1.0f + __expf(-hv.y));
    hv.z = hv.z / (1.0f + __expf(-hv.z));
    hv.w = hv.w / (1.0f + __expf(-hv.w));
    /* LayerNorm over 256 dims spread across 64 lanes x 4 */
    float s1 = hv.x + hv.y + hv.z + hv.w;
    float s2 = hv.x * hv.x + hv.y * hv.y + hv.z * hv.z + hv.w * hv.w;
#pragma unroll
    for (int off = 1; off < 64; off <<= 1) {
        s1 += __shfl_xor(s1, off, 64);
        s2 += __shfl_xor(s2, off, 64);
    }
    float mu = s1 * (1.0f / 256.0f);
    float var = s2 * (1.0f / 256.0f) - mu * mu;
    float rs = rsqrtf(var + LN_EPS);
    const float4 g4 = reinterpret_cast<const float4*>(gamma)[lane];
    const float4 be4 = reinterpret_cast<const float4*>(beta)[lane];
    float4 o;
    o.x = (hv.x - mu) * rs * g4.x + be4.x;
    o.y = (hv.y - mu) * rs * g4.y + be4.y;
    o.z = (hv.z - mu) * rs * g4.z + be4.z;
    o.w = (hv.w - mu) * rs * g4.w + be4.w;
    reinterpret_cast<float4*>(hout)[node * 64 + lane] = o;
}

extern "C" void kernel_launch(void* const* d_in, const int* in_sizes, int n_in,
                              void* d_out, int out_size, void* d_ws, size_t ws_size,
                              hipStream_t stream) {
    (void)in_sizes; (void)n_in; (void)out_size; (void)ws_size;
    const float* x         = (const float*)d_in[0];
    const int*   ei        = (const int*)d_in[1];
    const float* edge_attr = (const float*)d_in[2];
    const float* Wl        = (const float*)d_in[3];
    const float* bl        = (const float*)d_in[4];
    const float* Wr        = (const float*)d_in[5];
    const float* br        = (const float*)d_in[6];
    const float* We        = (const float*)d_in[7];
    const float* att       = (const float*)d_in[8];
    const float* bias      = (const float*)d_in[9];
    const float* gamma     = (const float*)d_in[10];
    const float* beta      = (const float*)d_in[11];

    char* ws = (char*)d_ws;
    int*   cnt     = (int*)(ws + OFF_CNT);
    int*   fill    = (int*)(ws + OFF_FILL);
    int*   row_ptr = (int*)(ws + OFF_ROWPTR);
    int*   eids    = (int*)(ws + OFF_EIDS);
    float* lattr   = (float*)(ws + OFF_LATTR);
    float* xl      = (float*)(ws + OFF_XL);
    float* xr      = (float*)(ws + OFF_XR);
    float* logits  = (float*)(ws + OFF_LOG);

    float* hout      = (float*)d_out;
    float* alpha_out = (float*)d_out + N_NODES * 256;

    hipMemsetAsync(ws + OFF_CNT, 0, 2 * N_NODES * sizeof(int), stream);

    k_count<<<(N_EDGES + 255) / 256, 256, 0, stream>>>(ei, cnt);
    k_scan<<<1, 256, 0, stream>>>(cnt, row_ptr);
    k_fill<<<(NE_TOT + 255) / 256, 256, 0, stream>>>(ei, row_ptr, fill, eids);
    k_loop_attr<<<N_NODES / 4, 256, 0, stream>>>(edge_attr, row_ptr, eids, cnt, lattr);
    k_gemm_xlxr<<<N_NODES / 8, 256, 0, stream>>>(x, Wl, bl, Wr, br, xl, xr);
    k_logits<<<512, 1024, 0, stream>>>(ei, edge_attr, lattr, xl, xr, We, att, logits);
    k_aggregate<<<N_NODES / 4, 256, 0, stream>>>(ei, row_ptr, eids, logits, xl,
                                                 bias, gamma, beta, hout, alpha_out);
}

// Round 2
// 915.849 us; speedup vs baseline: 2.7509x; 2.7509x over previous
//
#include <hip/hip_runtime.h>

#define N_NODES 10000
#define N_EDGES 320000
#define NE_TOT  330000   /* E + N */
#define NEG_SLOPE 0.2f
#define LN_EPS 1e-5f

/* workspace layout (bytes) */
#define OFF_CNT    0u         /* int[N]            */
#define OFF_FILL   40000u     /* int[N]            */
#define OFF_ROWPTR 80128u     /* int[N+1]          */
#define OFF_EIDS   120320u    /* int[E+N]          */
#define OFF_LATTR  1440512u   /* float[N*64]       */
#define OFF_XL     4000512u   /* float[N*256]      */
#define OFF_XR     14240512u  /* float[N*256]      */
#define OFF_LOG    24480512u  /* float[(E+N)*4]    */

__global__ void k_count(const int* __restrict__ ei, int* __restrict__ cnt) {
    int e = blockIdx.x * blockDim.x + threadIdx.x;
    if (e < N_EDGES) atomicAdd(&cnt[ei[N_EDGES + e]], 1);
}

__global__ void k_scan(const int* __restrict__ cnt, int* __restrict__ row_ptr) {
    __shared__ int sums[256];
    int t = threadIdx.x;
    const int CH = (N_NODES + 255) / 256;   /* 40 */
    int base = t * CH;
    int s = 0;
    for (int i = 0; i < CH; i++) {
        int n = base + i;
        if (n < N_NODES) s += cnt[n] + 1;   /* +1 self loop */
    }
    sums[t] = s;
    __syncthreads();
    for (int off = 1; off < 256; off <<= 1) {
        int v = (t >= off) ? sums[t - off] : 0;
        __syncthreads();
        sums[t] += v;
        __syncthreads();
    }
    int run = (t == 0) ? 0 : sums[t - 1];
    for (int i = 0; i < CH; i++) {
        int n = base + i;
        if (n < N_NODES) { row_ptr[n] = run; run += cnt[n] + 1; }
    }
    if (t == 255) row_ptr[N_NODES] = sums[255];
}

__global__ void k_fill(const int* __restrict__ ei, const int* __restrict__ row_ptr,
                       int* __restrict__ fill, int* __restrict__ eids) {
    int e = blockIdx.x * blockDim.x + threadIdx.x;
    if (e >= NE_TOT) return;
    int d = (e < N_EDGES) ? ei[N_EDGES + e] : (e - N_EDGES);
    int pos = atomicAdd(&fill[d], 1);
    eids[row_ptr[d] + pos] = e;
}

/* one wave per node: mean of incoming edge_attr (original edges only) */
__global__ void k_loop_attr(const float* __restrict__ edge_attr,
                            const int* __restrict__ row_ptr,
                            const int* __restrict__ eids,
                            const int* __restrict__ cnt,
                            float* __restrict__ lattr) {
    int node = (blockIdx.x << 2) + (threadIdx.x >> 6);
    int lane = threadIdx.x & 63;
    int b = row_ptr[node], en = row_ptr[node + 1];
    float s = 0.0f;
    for (int i = b; i < en; i++) {
        int e = eids[i];
        if (e < N_EDGES) s += edge_attr[e * 64 + lane];
    }
    float c = (float)cnt[node];
    lattr[node * 64 + lane] = s / fmaxf(c, 1.0f);
}

/* xl = x@Wl^T + bl ; xr = x@Wr^T + br.  8 nodes per 256-thread block. */
__global__ void k_gemm_xlxr(const float* __restrict__ x,
                            const float* __restrict__ Wl, const float* __restrict__ bl,
                            const float* __restrict__ Wr, const float* __restrict__ br,
                            float* __restrict__ xl, float* __restrict__ xr) {
    __shared__ float xs[8][256];
    int t = threadIdx.x;
    int nb = blockIdx.x * 8;
#pragma unroll
    for (int nn = 0; nn < 8; nn++) xs[nn][t] = x[(nb + nn) * 256 + t];
    __syncthreads();

    float accl[8], accr[8];
    float b0 = bl[t], b1 = br[t];
#pragma unroll
    for (int nn = 0; nn < 8; nn++) { accl[nn] = b0; accr[nn] = b1; }

    const float4* wl4 = reinterpret_cast<const float4*>(Wl) + t * 64;
    const float4* wr4 = reinterpret_cast<const float4*>(Wr) + t * 64;
    for (int i = 0; i < 64; i++) {
        float4 wl = wl4[i];
        float4 wr = wr4[i];
#pragma unroll
        for (int nn = 0; nn < 8; nn++) {
            float4 xv = reinterpret_cast<const float4*>(xs[nn])[i];
            accl[nn] = fmaf(xv.x, wl.x, accl[nn]);
            accl[nn] = fmaf(xv.y, wl.y, accl[nn]);
            accl[nn] = fmaf(xv.z, wl.z, accl[nn]);
            accl[nn] = fmaf(xv.w, wl.w, accl[nn]);
            accr[nn] = fmaf(xv.x, wr.x, accr[nn]);
            accr[nn] = fmaf(xv.y, wr.y, accr[nn]);
            accr[nn] = fmaf(xv.z, wr.z, accr[nn]);
            accr[nn] = fmaf(xv.w, wr.w, accr[nn]);
        }
    }
#pragma unroll
    for (int nn = 0; nn < 8; nn++) {
        xl[(nb + nn) * 256 + t] = accl[nn];
        xr[(nb + nn) * 256 + t] = accr[nn];
    }
}

/* logits: ONE THREAD PER EDGE, fully fused, no LDS.
   ea row (64 f32) held in VGPRs; We/att read through provably-uniform
   indices -> scalar loads (s_load) on the SMEM path; xl/xr rows consumed
   fully per thread so every fetched line is used; coalesced float4 store. */
__global__ __launch_bounds__(256) void k_logits(
                         const int* __restrict__ ei,
                         const float* __restrict__ edge_attr,
                         const float* __restrict__ lattr,
                         const float* __restrict__ xl, const float* __restrict__ xr,
                         const float* __restrict__ We, const float* __restrict__ att,
                         float* __restrict__ logits) {
    int e = blockIdx.x * 256 + threadIdx.x;
    bool active = (e < NE_TOT);
    int s = 0, d = 0;
    const float* ea_row = edge_attr;
    if (active) {
        if (e < N_EDGES) {
            s = ei[e];
            d = ei[N_EDGES + e];
            ea_row = edge_attr + (size_t)e * 64;
        } else {
            s = e - N_EDGES;
            d = s;
            ea_row = lattr + (size_t)(e - N_EDGES) * 64;
        }
    }

    float ea[64];
#pragma unroll
    for (int k4 = 0; k4 < 16; k4++) {
        float4 v = reinterpret_cast<const float4*>(ea_row)[k4];
        ea[k4 * 4 + 0] = v.x;
        ea[k4 * 4 + 1] = v.y;
        ea[k4 * 4 + 2] = v.z;
        ea[k4 * 4 + 3] = v.w;
    }

    const float4* xl4 = reinterpret_cast<const float4*>(xl) + (size_t)s * 64;
    const float4* xr4 = reinterpret_cast<const float4*>(xr) + (size_t)d * 64;

    float vh[4];
#pragma unroll
    for (int h = 0; h < 4; h++) {
        float acc = 0.0f;
        for (int c4 = 0; c4 < 16; c4++) {       /* c = h*64 + c4*4 + j */
            float4 a = xl4[h * 16 + c4];
            float4 b = xr4[h * 16 + c4];
            float m[4];
            m[0] = a.x + b.x; m[1] = a.y + b.y; m[2] = a.z + b.z; m[3] = a.w + b.w;
#pragma unroll
            for (int j = 0; j < 4; j++) {
                int c = h * 64 + c4 * 4 + j;
                float ep = 0.0f;
#pragma unroll
                for (int k = 0; k < 64; k++) {
                    ep = fmaf(ea[k], We[c * 64 + k], ep);   /* uniform -> s_load */
                }
                float mm = m[j] + ep;
                mm = (mm >= 0.0f) ? mm : NEG_SLOPE * mm;
                acc = fmaf(mm, att[c], acc);                 /* uniform -> s_load */
            }
        }
        vh[h] = acc;
    }

    if (active) {
        reinterpret_cast<float4*>(logits)[e] = make_float4(vh[0], vh[1], vh[2], vh[3]);
    }
}

/* one wave per node: segment softmax + weighted sum + bias + SiLU + LayerNorm */
__global__ void k_aggregate(const int* __restrict__ ei,
                            const int* __restrict__ row_ptr,
                            const int* __restrict__ eids,
                            const float* __restrict__ logits,
                            const float* __restrict__ xl,
                            const float* __restrict__ bias,
                            const float* __restrict__ gamma,
                            const float* __restrict__ beta,
                            float* __restrict__ hout,
                            float* __restrict__ alpha_out) {
    int node = (blockIdx.x << 2) + (threadIdx.x >> 6);
    int lane = threadIdx.x & 63;
    int h = lane >> 4;
    int b = row_ptr[node], en = row_ptr[node + 1];

    float mh = -INFINITY;
    for (int i = b; i < en; i++) {
        int e = eids[i];
        mh = fmaxf(mh, logits[e * 4 + h]);
    }
    float den = 0.0f;
    for (int i = b; i < en; i++) {
        int e = eids[i];
        den += __expf(logits[e * 4 + h] - mh);
    }
    float rden = 1.0f / den;

    const float4* xl4p = reinterpret_cast<const float4*>(xl);
    float4 acc; acc.x = acc.y = acc.z = acc.w = 0.0f;
    for (int i = b; i < en; i++) {
        int e = eids[i];
        float al = __expf(logits[e * 4 + h] - mh) * rden;
        if ((lane & 15) == 0) alpha_out[e * 4 + h] = al;
        int s = (e < N_EDGES) ? ei[e] : (e - N_EDGES);
        float4 xv = xl4p[s * 64 + lane];
        acc.x = fmaf(al, xv.x, acc.x);
        acc.y = fmaf(al, xv.y, acc.y);
        acc.z = fmaf(al, xv.z, acc.z);
        acc.w = fmaf(al, xv.w, acc.w);
    }

    const float4 b4 = reinterpret_cast<const float4*>(bias)[lane];
    float4 hv;
    hv.x = acc.x + b4.x; hv.y = acc.y + b4.y;
    hv.z = acc.z + b4.z; hv.w = acc.w + b4.w;
    /* SiLU */
    hv.x = hv.x / (1.0f + __expf(-hv.x));
    hv.y = hv.y / (1.0f + __expf(-hv.y));
    hv.z = hv.z / (1.0f + __expf(-hv.z));
    hv.w = hv.w / (1.0f + __expf(-hv.w));
    /* LayerNorm over 256 dims spread across 64 lanes x 4 */
    float s1 = hv.x + hv.y + hv.z + hv.w;
    float s2 = hv.x * hv.x + hv.y * hv.y + hv.z * hv.z + hv.w * hv.w;
#pragma unroll
    for (int off = 1; off < 64; off <<= 1) {
        s1 += __shfl_xor(s1, off, 64);
        s2 += __shfl_xor(s2, off, 64);
    }
    float mu = s1 * (1.0f / 256.0f);
    float var = s2 * (1.0f / 256.0f) - mu * mu;
    float rs = rsqrtf(var + LN_EPS);
    const float4 g4 = reinterpret_cast<const float4*>(gamma)[lane];
    const float4 be4 = reinterpret_cast<const float4*>(beta)[lane];
    float4 o;
    o.x = (hv.x - mu) * rs * g4.x + be4.x;
    o.y = (hv.y - mu) * rs * g4.y + be4.y;
    o.z = (hv.z - mu) * rs * g4.z + be4.z;
    o.w = (hv.w - mu) * rs * g4.w + be4.w;
    reinterpret_cast<float4*>(hout)[node * 64 + lane] = o;
}

extern "C" void kernel_launch(void* const* d_in, const int* in_sizes, int n_in,
                              void* d_out, int out_size, void* d_ws, size_t ws_size,
                              hipStream_t stream) {
    (void)in_sizes; (void)n_in; (void)out_size; (void)ws_size;
    const float* x         = (const float*)d_in[0];
    const int*   ei        = (const int*)d_in[1];
    const float* edge_attr = (const float*)d_in[2];
    const float* Wl        = (const float*)d_in[3];
    const float* bl        = (const float*)d_in[4];
    const float* Wr        = (const float*)d_in[5];
    const float* br        = (const float*)d_in[6];
    const float* We        = (const float*)d_in[7];
    const float* att       = (const float*)d_in[8];
    const float* bias      = (const float*)d_in[9];
    const float* gamma     = (const float*)d_in[10];
    const float* beta      = (const float*)d_in[11];

    char* ws = (char*)d_ws;
    int*   cnt     = (int*)(ws + OFF_CNT);
    int*   fill    = (int*)(ws + OFF_FILL);
    int*   row_ptr = (int*)(ws + OFF_ROWPTR);
    int*   eids    = (int*)(ws + OFF_EIDS);
    float* lattr   = (float*)(ws + OFF_LATTR);
    float* xl      = (float*)(ws + OFF_XL);
    float* xr      = (float*)(ws + OFF_XR);
    float* logits  = (float*)(ws + OFF_LOG);

    float* hout      = (float*)d_out;
    float* alpha_out = (float*)d_out + N_NODES * 256;

    hipMemsetAsync(ws + OFF_CNT, 0, 2 * N_NODES * sizeof(int), stream);

    k_count<<<(N_EDGES + 255) / 256, 256, 0, stream>>>(ei, cnt);
    k_scan<<<1, 256, 0, stream>>>(cnt, row_ptr);
    k_fill<<<(NE_TOT + 255) / 256, 256, 0, stream>>>(ei, row_ptr, fill, eids);
    k_loop_attr<<<N_NODES / 4, 256, 0, stream>>>(edge_attr, row_ptr, eids, cnt, lattr);
    k_gemm_xlxr<<<N_NODES / 8, 256, 0, stream>>>(x, Wl, bl, Wr, br, xl, xr);
    k_logits<<<(NE_TOT + 255) / 256, 256, 0, stream>>>(ei, edge_attr, lattr, xl, xr, We, att, logits);
    k_aggregate<<<N_NODES / 4, 256, 0, stream>>>(ei, row_ptr, eids, logits, xl,
                                                 bias, gamma, beta, hout, alpha_out);
}

// Round 3
// 765.853 us; speedup vs baseline: 3.2897x; 1.1959x over previous
//
#include <hip/hip_runtime.h>

#define N_NODES 10000
#define N_EDGES 320000
#define NE_TOT  330000   /* E + N */
#define NEG_SLOPE 0.2f
#define LN_EPS 1e-5f

/* workspace layout (bytes) */
#define OFF_CNT    0u         /* int[N]            */
#define OFF_FILL   40000u     /* int[N]            */
#define OFF_ROWPTR 80128u     /* int[N+1]          */
#define OFF_EIDS   120320u    /* int[E+N]          */
#define OFF_LATTR  1440512u   /* float[N*64]       */
#define OFF_XL     4000512u   /* float[N*256]      */
#define OFF_XR     14240512u  /* float[N*256]      */
#define OFF_LOG    24480512u  /* float[(E+N)*4]    */

typedef __bf16 bf16x8 __attribute__((ext_vector_type(8)));
typedef float  f32x16 __attribute__((ext_vector_type(16)));

__global__ void k_count(const int* __restrict__ ei, int* __restrict__ cnt) {
    int e = blockIdx.x * blockDim.x + threadIdx.x;
    if (e < N_EDGES) atomicAdd(&cnt[ei[N_EDGES + e]], 1);
}

__global__ void k_scan(const int* __restrict__ cnt, int* __restrict__ row_ptr) {
    __shared__ int sums[256];
    int t = threadIdx.x;
    const int CH = (N_NODES + 255) / 256;   /* 40 */
    int base = t * CH;
    int s = 0;
    for (int i = 0; i < CH; i++) {
        int n = base + i;
        if (n < N_NODES) s += cnt[n] + 1;   /* +1 self loop */
    }
    sums[t] = s;
    __syncthreads();
    for (int off = 1; off < 256; off <<= 1) {
        int v = (t >= off) ? sums[t - off] : 0;
        __syncthreads();
        sums[t] += v;
        __syncthreads();
    }
    int run = (t == 0) ? 0 : sums[t - 1];
    for (int i = 0; i < CH; i++) {
        int n = base + i;
        if (n < N_NODES) { row_ptr[n] = run; run += cnt[n] + 1; }
    }
    if (t == 255) row_ptr[N_NODES] = sums[255];
}

__global__ void k_fill(const int* __restrict__ ei, const int* __restrict__ row_ptr,
                       int* __restrict__ fill, int* __restrict__ eids) {
    int e = blockIdx.x * blockDim.x + threadIdx.x;
    if (e >= NE_TOT) return;
    int d = (e < N_EDGES) ? ei[N_EDGES + e] : (e - N_EDGES);
    int pos = atomicAdd(&fill[d], 1);
    eids[row_ptr[d] + pos] = e;
}

/* one wave per node: mean of incoming edge_attr (original edges only) */
__global__ void k_loop_attr(const float* __restrict__ edge_attr,
                            const int* __restrict__ row_ptr,
                            const int* __restrict__ eids,
                            const int* __restrict__ cnt,
                            float* __restrict__ lattr) {
    int node = (blockIdx.x << 2) + (threadIdx.x >> 6);
    int lane = threadIdx.x & 63;
    int b = row_ptr[node], en = row_ptr[node + 1];
    float s = 0.0f;
    for (int i = b; i < en; i++) {
        int e = eids[i];
        if (e < N_EDGES) s += edge_attr[e * 64 + lane];
    }
    float c = (float)cnt[node];
    lattr[node * 64 + lane] = s / fmaxf(c, 1.0f);
}

/* xl = x@Wl^T + bl ; xr = x@Wr^T + br.  8 nodes per 256-thread block. */
__global__ void k_gemm_xlxr(const float* __restrict__ x,
                            const float* __restrict__ Wl, const float* __restrict__ bl,
                            const float* __restrict__ Wr, const float* __restrict__ br,
                            float* __restrict__ xl, float* __restrict__ xr) {
    __shared__ float xs[8][256];
    int t = threadIdx.x;
    int nb = blockIdx.x * 8;
#pragma unroll
    for (int nn = 0; nn < 8; nn++) xs[nn][t] = x[(nb + nn) * 256 + t];
    __syncthreads();

    float accl[8], accr[8];
    float b0 = bl[t], b1 = br[t];
#pragma unroll
    for (int nn = 0; nn < 8; nn++) { accl[nn] = b0; accr[nn] = b1; }

    const float4* wl4 = reinterpret_cast<const float4*>(Wl) + t * 64;
    const float4* wr4 = reinterpret_cast<const float4*>(Wr) + t * 64;
    for (int i = 0; i < 64; i++) {
        float4 wl = wl4[i];
        float4 wr = wr4[i];
#pragma unroll
        for (int nn = 0; nn < 8; nn++) {
            float4 xv = reinterpret_cast<const float4*>(xs[nn])[i];
            accl[nn] = fmaf(xv.x, wl.x, accl[nn]);
            accl[nn] = fmaf(xv.y, wl.y, accl[nn]);
            accl[nn] = fmaf(xv.z, wl.z, accl[nn]);
            accl[nn] = fmaf(xv.w, wl.w, accl[nn]);
            accr[nn] = fmaf(xv.x, wr.x, accr[nn]);
            accr[nn] = fmaf(xv.y, wr.y, accr[nn]);
            accr[nn] = fmaf(xv.z, wr.z, accr[nn]);
            accr[nn] = fmaf(xv.w, wr.w, accr[nn]);
        }
    }
#pragma unroll
    for (int nn = 0; nn < 8; nn++) {
        xl[(nb + nn) * 256 + t] = accl[nn];
        xr[(nb + nn) * 256 + t] = accr[nn];
    }
}

/* logits via MFMA: one wave = 32-edge tile.
   ep = ea(bf16) @ WeT(bf16) on matrix pipe; WeT staged once per block in LDS
   in fragment order (conflict-free ds_read_b128). Epilogue in C-layout:
   coalesced xl/xr row reads, lrelu, att-dot, shfl_xor reduce over c.
   mfma_f32_32x32x16_bf16: A[m=lane&31][k=(lane>>5)*8+j];
   B[k=(lane>>5)*8+j][n=lane&31]; C: col=lane&31, row=(r&3)+8*(r>>2)+4*(lane>>5). */
__global__ __launch_bounds__(256) void k_logits_mfma(
        const int* __restrict__ ei,
        const float* __restrict__ edge_attr,
        const float* __restrict__ lattr,
        const float* __restrict__ xl, const float* __restrict__ xr,
        const float* __restrict__ We, const float* __restrict__ att,
        float* __restrict__ logits) {
    __shared__ __bf16 fb[32 * 64 * 8];   /* [frag f=nt*4+ks][lane][8], 32 KB */
    int tid = threadIdx.x;

    /* build B fragments (We is [c=256][k=64] row-major) */
    for (int idx = tid; idx < 2048; idx += 256) {
        int f = idx >> 6, ls = idx & 63;
        int nt = f >> 2, ks = f & 3;
        int c = nt * 32 + (ls & 31);
        int kb = ks * 16 + (ls >> 5) * 8;
        const float* w = We + c * 64 + kb;
        float4 a0 = *reinterpret_cast<const float4*>(w);
        float4 a1 = *reinterpret_cast<const float4*>(w + 4);
        bf16x8 t;
        t[0] = (__bf16)a0.x; t[1] = (__bf16)a0.y; t[2] = (__bf16)a0.z; t[3] = (__bf16)a0.w;
        t[4] = (__bf16)a1.x; t[5] = (__bf16)a1.y; t[6] = (__bf16)a1.z; t[7] = (__bf16)a1.w;
        *reinterpret_cast<bf16x8*>(&fb[idx * 8]) = t;
    }
    __syncthreads();

    int lane = tid & 63;
    int wv = tid >> 6;
    int half = lane >> 5;
    int ln31 = lane & 31;

    float attv[8];
#pragma unroll
    for (int g = 0; g < 8; g++) attv[g] = att[g * 32 + ln31];

    const int ntiles = (NE_TOT + 31) / 32;   /* 10313 */
    for (int t = blockIdx.x * 4 + wv; t < ntiles; t += gridDim.x * 4) {
        int t0 = t * 32;
        int e = t0 + ln31;
        int ec = (e < NE_TOT) ? e : (NE_TOT - 1);
        int s, d;
        const float* row;
        if (ec < N_EDGES) {
            s = ei[ec]; d = ei[N_EDGES + ec];
            row = edge_attr + (size_t)ec * 64;
        } else {
            s = ec - N_EDGES; d = s;
            row = lattr + (size_t)(ec - N_EDGES) * 64;
        }

        /* A fragments: lane holds edge (ln31)'s ea[k], k = half*8 + ks*16 + j */
        bf16x8 af[4];
#pragma unroll
        for (int ks = 0; ks < 4; ks++) {
            const float* p = row + half * 8 + ks * 16;
            float4 v0 = *reinterpret_cast<const float4*>(p);
            float4 v1 = *reinterpret_cast<const float4*>(p + 4);
            af[ks][0] = (__bf16)v0.x; af[ks][1] = (__bf16)v0.y;
            af[ks][2] = (__bf16)v0.z; af[ks][3] = (__bf16)v0.w;
            af[ks][4] = (__bf16)v1.x; af[ks][5] = (__bf16)v1.y;
            af[ks][6] = (__bf16)v1.z; af[ks][7] = (__bf16)v1.w;
        }

#pragma unroll
        for (int p = 0; p < 2; p++) {          /* c-halves: heads 2p, 2p+1 */
            f32x16 acc[4];
#pragma unroll
            for (int nt = 0; nt < 4; nt++)
#pragma unroll
                for (int j = 0; j < 16; j++) acc[nt][j] = 0.0f;

#pragma unroll
            for (int ks = 0; ks < 4; ks++) {
#pragma unroll
                for (int nt = 0; nt < 4; nt++) {
                    bf16x8 b = *reinterpret_cast<const bf16x8*>(
                        &fb[((((p * 4 + nt) * 4 + ks) * 64) + lane) * 8]);
                    acc[nt] = __builtin_amdgcn_mfma_f32_32x32x16_bf16(
                        af[ks], b, acc[nt], 0, 0, 0);
                }
            }

            /* epilogue */
#pragma unroll
            for (int r = 0; r < 16; r++) {
                int m = (r & 3) + 8 * (r >> 2) + 4 * half;
                int sm = __shfl(s, m, 64);
                int dm = __shfl(d, m, 64);
                const float* xlr = xl + (size_t)sm * 256 + ln31;
                const float* xrr = xr + (size_t)dm * 256 + ln31;
                float h0 = 0.0f, h1 = 0.0f;
#pragma unroll
                for (int nt = 0; nt < 4; nt++) {
                    int g = p * 4 + nt;
                    float v = acc[nt][r] + xlr[g * 32] + xrr[g * 32];
                    v = (v >= 0.0f) ? v : NEG_SLOPE * v;
                    v *= attv[g];
                    if (nt < 2) h0 += v; else h1 += v;
                }
#pragma unroll
                for (int off = 1; off < 32; off <<= 1) {
                    h0 += __shfl_xor(h0, off, 64);
                    h1 += __shfl_xor(h1, off, 64);
                }
                if (ln31 == 0) {
                    int ee = t0 + m;
                    if (ee < NE_TOT) {
                        logits[ee * 4 + p * 2 + 0] = h0;
                        logits[ee * 4 + p * 2 + 1] = h1;
                    }
                }
            }
        }
    }
}

/* one wave per node: segment softmax + weighted sum + bias + SiLU + LayerNorm */
__global__ void k_aggregate(const int* __restrict__ ei,
                            const int* __restrict__ row_ptr,
                            const int* __restrict__ eids,
                            const float* __restrict__ logits,
                            const float* __restrict__ xl,
                            const float* __restrict__ bias,
                            const float* __restrict__ gamma,
                            const float* __restrict__ beta,
                            float* __restrict__ hout,
                            float* __restrict__ alpha_out) {
    int node = (blockIdx.x << 2) + (threadIdx.x >> 6);
    int lane = threadIdx.x & 63;
    int h = lane >> 4;
    int b = row_ptr[node], en = row_ptr[node + 1];

    float mh = -INFINITY;
    for (int i = b; i < en; i++) {
        int e = eids[i];
        mh = fmaxf(mh, logits[e * 4 + h]);
    }
    float den = 0.0f;
    for (int i = b; i < en; i++) {
        int e = eids[i];
        den += __expf(logits[e * 4 + h] - mh);
    }
    float rden = 1.0f / den;

    const float4* xl4p = reinterpret_cast<const float4*>(xl);
    float4 acc; acc.x = acc.y = acc.z = acc.w = 0.0f;
    for (int i = b; i < en; i++) {
        int e = eids[i];
        float al = __expf(logits[e * 4 + h] - mh) * rden;
        if ((lane & 15) == 0) alpha_out[e * 4 + h] = al;
        int s = (e < N_EDGES) ? ei[e] : (e - N_EDGES);
        float4 xv = xl4p[s * 64 + lane];
        acc.x = fmaf(al, xv.x, acc.x);
        acc.y = fmaf(al, xv.y, acc.y);
        acc.z = fmaf(al, xv.z, acc.z);
        acc.w = fmaf(al, xv.w, acc.w);
    }

    const float4 b4 = reinterpret_cast<const float4*>(bias)[lane];
    float4 hv;
    hv.x = acc.x + b4.x; hv.y = acc.y + b4.y;
    hv.z = acc.z + b4.z; hv.w = acc.w + b4.w;
    /* SiLU */
    hv.x = hv.x / (1.0f + __expf(-hv.x));
    hv.y = hv.y / (1.0f + __expf(-hv.y));
    hv.z = hv.z / (1.0f + __expf(-hv.z));
    hv.w = hv.w / (1.0f + __expf(-hv.w));
    /* LayerNorm over 256 dims spread across 64 lanes x 4 */
    float s1 = hv.x + hv.y + hv.z + hv.w;
    float s2 = hv.x * hv.x + hv.y * hv.y + hv.z * hv.z + hv.w * hv.w;
#pragma unroll
    for (int off = 1; off < 64; off <<= 1) {
        s1 += __shfl_xor(s1, off, 64);
        s2 += __shfl_xor(s2, off, 64);
    }
    float mu = s1 * (1.0f / 256.0f);
    float var = s2 * (1.0f / 256.0f) - mu * mu;
    float rs = rsqrtf(var + LN_EPS);
    const float4 g4 = reinterpret_cast<const float4*>(gamma)[lane];
    const float4 be4 = reinterpret_cast<const float4*>(beta)[lane];
    float4 o;
    o.x = (hv.x - mu) * rs * g4.x + be4.x;
    o.y = (hv.y - mu) * rs * g4.y + be4.y;
    o.z = (hv.z - mu) * rs * g4.z + be4.z;
    o.w = (hv.w - mu) * rs * g4.w + be4.w;
    reinterpret_cast<float4*>(hout)[node * 64 + lane] = o;
}

extern "C" void kernel_launch(void* const* d_in, const int* in_sizes, int n_in,
                              void* d_out, int out_size, void* d_ws, size_t ws_size,
                              hipStream_t stream) {
    (void)in_sizes; (void)n_in; (void)out_size; (void)ws_size;
    const float* x         = (const float*)d_in[0];
    const int*   ei        = (const int*)d_in[1];
    const float* edge_attr = (const float*)d_in[2];
    const float* Wl        = (const float*)d_in[3];
    const float* bl        = (const float*)d_in[4];
    const float* Wr        = (const float*)d_in[5];
    const float* br        = (const float*)d_in[6];
    const float* We        = (const float*)d_in[7];
    const float* att       = (const float*)d_in[8];
    const float* bias      = (const float*)d_in[9];
    const float* gamma     = (const float*)d_in[10];
    const float* beta      = (const float*)d_in[11];

    char* ws = (char*)d_ws;
    int*   cnt     = (int*)(ws + OFF_CNT);
    int*   fill    = (int*)(ws + OFF_FILL);
    int*   row_ptr = (int*)(ws + OFF_ROWPTR);
    int*   eids    = (int*)(ws + OFF_EIDS);
    float* lattr   = (float*)(ws + OFF_LATTR);
    float* xl      = (float*)(ws + OFF_XL);
    float* xr      = (float*)(ws + OFF_XR);
    float* logits  = (float*)(ws + OFF_LOG);

    float* hout      = (float*)d_out;
    float* alpha_out = (float*)d_out + N_NODES * 256;

    hipMemsetAsync(ws + OFF_CNT, 0, 2 * N_NODES * sizeof(int), stream);

    k_count<<<(N_EDGES + 255) / 256, 256, 0, stream>>>(ei, cnt);
    k_scan<<<1, 256, 0, stream>>>(cnt, row_ptr);
    k_fill<<<(NE_TOT + 255) / 256, 256, 0, stream>>>(ei, row_ptr, fill, eids);
    k_loop_attr<<<N_NODES / 4, 256, 0, stream>>>(edge_attr, row_ptr, eids, cnt, lattr);
    k_gemm_xlxr<<<N_NODES / 8, 256, 0, stream>>>(x, Wl, bl, Wr, br, xl, xr);
    k_logits_mfma<<<645, 256, 0, stream>>>(ei, edge_attr, lattr, xl, xr, We, att, logits);
    k_aggregate<<<N_NODES / 4, 256, 0, stream>>>(ei, row_ptr, eids, logits, xl,
                                                 bias, gamma, beta, hout, alpha_out);
}

// Round 4
// 686.101 us; speedup vs baseline: 3.6721x; 1.1162x over previous
//
#include <hip/hip_runtime.h>

#define N_NODES 10000
#define N_EDGES 320000
#define NE_TOT  330000   /* E + N */
#define NEG_SLOPE 0.2f
#define LN_EPS 1e-5f

/* workspace layout (bytes) */
#define OFF_CNT    0u         /* int[N]            */
#define OFF_FILL   40000u     /* int[N]            */
#define OFF_ROWPTR 80128u     /* int[N+1]          */
#define OFF_EIDS   120320u    /* int[E+N]          */
#define OFF_LATTR  1440512u   /* float[N*64]       */
#define OFF_XL     4000512u   /* float[N*256]      */
#define OFF_XR     14240512u  /* float[N*256]      */
#define OFF_LOG    24480512u  /* float[(E+N)*4]    */

typedef __bf16 bf16x8 __attribute__((ext_vector_type(8)));
typedef float  f32x16 __attribute__((ext_vector_type(16)));

__global__ void k_count(const int* __restrict__ ei, int* __restrict__ cnt) {
    int e = blockIdx.x * blockDim.x + threadIdx.x;
    if (e < N_EDGES) atomicAdd(&cnt[ei[N_EDGES + e]], 1);
}

__global__ void k_scan(const int* __restrict__ cnt, int* __restrict__ row_ptr) {
    __shared__ int sums[256];
    int t = threadIdx.x;
    const int CH = (N_NODES + 255) / 256;   /* 40 */
    int base = t * CH;
    int s = 0;
    for (int i = 0; i < CH; i++) {
        int n = base + i;
        if (n < N_NODES) s += cnt[n] + 1;   /* +1 self loop */
    }
    sums[t] = s;
    __syncthreads();
    for (int off = 1; off < 256; off <<= 1) {
        int v = (t >= off) ? sums[t - off] : 0;
        __syncthreads();
        sums[t] += v;
        __syncthreads();
    }
    int run = (t == 0) ? 0 : sums[t - 1];
    for (int i = 0; i < CH; i++) {
        int n = base + i;
        if (n < N_NODES) { row_ptr[n] = run; run += cnt[n] + 1; }
    }
    if (t == 255) row_ptr[N_NODES] = sums[255];
}

__global__ void k_fill(const int* __restrict__ ei, const int* __restrict__ row_ptr,
                       int* __restrict__ fill, int* __restrict__ eids) {
    int e = blockIdx.x * blockDim.x + threadIdx.x;
    if (e >= NE_TOT) return;
    int d = (e < N_EDGES) ? ei[N_EDGES + e] : (e - N_EDGES);
    int pos = atomicAdd(&fill[d], 1);
    eids[row_ptr[d] + pos] = e;
}

/* one wave per node: mean of incoming edge_attr (original edges only) */
__global__ void k_loop_attr(const float* __restrict__ edge_attr,
                            const int* __restrict__ row_ptr,
                            const int* __restrict__ eids,
                            const int* __restrict__ cnt,
                            float* __restrict__ lattr) {
    int node = (blockIdx.x << 2) + (threadIdx.x >> 6);
    int lane = threadIdx.x & 63;
    int b = row_ptr[node], en = row_ptr[node + 1];
    float s = 0.0f;
    for (int i = b; i < en; i++) {
        int e = eids[i];
        if (e < N_EDGES) s += edge_attr[e * 64 + lane];
    }
    float c = (float)cnt[node];
    lattr[node * 64 + lane] = s / fmaxf(c, 1.0f);
}

/* xl = x@Wl^T + bl ; xr = x@Wr^T + br.  8 nodes per 256-thread block. */
__global__ void k_gemm_xlxr(const float* __restrict__ x,
                            const float* __restrict__ Wl, const float* __restrict__ bl,
                            const float* __restrict__ Wr, const float* __restrict__ br,
                            float* __restrict__ xl, float* __restrict__ xr) {
    __shared__ float xs[8][256];
    int t = threadIdx.x;
    int nb = blockIdx.x * 8;
#pragma unroll
    for (int nn = 0; nn < 8; nn++) xs[nn][t] = x[(nb + nn) * 256 + t];
    __syncthreads();

    float accl[8], accr[8];
    float b0 = bl[t], b1 = br[t];
#pragma unroll
    for (int nn = 0; nn < 8; nn++) { accl[nn] = b0; accr[nn] = b1; }

    const float4* wl4 = reinterpret_cast<const float4*>(Wl) + t * 64;
    const float4* wr4 = reinterpret_cast<const float4*>(Wr) + t * 64;
    for (int i = 0; i < 64; i++) {
        float4 wl = wl4[i];
        float4 wr = wr4[i];
#pragma unroll
        for (int nn = 0; nn < 8; nn++) {
            float4 xv = reinterpret_cast<const float4*>(xs[nn])[i];
            accl[nn] = fmaf(xv.x, wl.x, accl[nn]);
            accl[nn] = fmaf(xv.y, wl.y, accl[nn]);
            accl[nn] = fmaf(xv.z, wl.z, accl[nn]);
            accl[nn] = fmaf(xv.w, wl.w, accl[nn]);
            accr[nn] = fmaf(xv.x, wr.x, accr[nn]);
            accr[nn] = fmaf(xv.y, wr.y, accr[nn]);
            accr[nn] = fmaf(xv.z, wr.z, accr[nn]);
            accr[nn] = fmaf(xv.w, wr.w, accr[nn]);
        }
    }
#pragma unroll
    for (int nn = 0; nn < 8; nn++) {
        xl[(nb + nn) * 256 + t] = accl[nn];
        xr[(nb + nn) * 256 + t] = accr[nn];
    }
}

/* logits via MFMA, operand-swapped: acc = We_frag (A) * ea_frag (B) = ep^T.
   C cols = edges -> lane ln31 holds edge t0+ln31's c-values in-register.
   Epilogue: per-lane float4 gathers of own edge's xl/xr/att chunks, lrelu +
   att-dot reduced in-register, one shfl_xor(32) per head, float4 store.
   mfma_32x32x16 layouts: A[m=lane&31][k=(lane>>5)*8+j] (m = c here),
   B[k=(lane>>5)*8+j][n=lane&31] (n = edge), C[row=(r&3)+8*(r>>2)+4*(lane>>5)]
   [col=lane&31] -> row = c-within-block, col = edge. */
__global__ __launch_bounds__(256) void k_logits_mfma(
        const int* __restrict__ ei,
        const float* __restrict__ edge_attr,
        const float* __restrict__ lattr,
        const float* __restrict__ xl, const float* __restrict__ xr,
        const float* __restrict__ We, const float* __restrict__ att,
        float* __restrict__ logits) {
    __shared__ __bf16 fb[32 * 64 * 8];   /* [frag f=g*4+ks][lane][8], 32 KB */
    int tid = threadIdx.x;

    /* build We fragments (We is [c=256][k=64] row-major) */
    for (int idx = tid; idx < 2048; idx += 256) {
        int f = idx >> 6, ls = idx & 63;
        int g = f >> 2, ks = f & 3;
        int c = g * 32 + (ls & 31);
        int kb = ks * 16 + (ls >> 5) * 8;
        const float* w = We + c * 64 + kb;
        float4 a0 = *reinterpret_cast<const float4*>(w);
        float4 a1 = *reinterpret_cast<const float4*>(w + 4);
        bf16x8 t;
        t[0] = (__bf16)a0.x; t[1] = (__bf16)a0.y; t[2] = (__bf16)a0.z; t[3] = (__bf16)a0.w;
        t[4] = (__bf16)a1.x; t[5] = (__bf16)a1.y; t[6] = (__bf16)a1.z; t[7] = (__bf16)a1.w;
        *reinterpret_cast<bf16x8*>(&fb[idx * 8]) = t;
    }
    __syncthreads();

    int lane = tid & 63;
    int wv = tid >> 6;
    int half = lane >> 5;
    int ln31 = lane & 31;

    const int ntiles = (NE_TOT + 31) / 32;   /* 10313 */
    for (int t = blockIdx.x * 4 + wv; t < ntiles; t += gridDim.x * 4) {
        int t0 = t * 32;
        int e = t0 + ln31;
        int ec = (e < NE_TOT) ? e : (NE_TOT - 1);
        int s, d;
        const float* row;
        if (ec < N_EDGES) {
            s = ei[ec]; d = ei[N_EDGES + ec];
            row = edge_attr + (size_t)ec * 64;
        } else {
            s = ec - N_EDGES; d = s;
            row = lattr + (size_t)(ec - N_EDGES) * 64;
        }

        /* B fragments: lane holds edge (ln31)'s ea[k], k = half*8 + ks*16 + j */
        bf16x8 af[4];
#pragma unroll
        for (int ks = 0; ks < 4; ks++) {
            const float* p = row + half * 8 + ks * 16;
            float4 v0 = *reinterpret_cast<const float4*>(p);
            float4 v1 = *reinterpret_cast<const float4*>(p + 4);
            af[ks][0] = (__bf16)v0.x; af[ks][1] = (__bf16)v0.y;
            af[ks][2] = (__bf16)v0.z; af[ks][3] = (__bf16)v0.w;
            af[ks][4] = (__bf16)v1.x; af[ks][5] = (__bf16)v1.y;
            af[ks][6] = (__bf16)v1.z; af[ks][7] = (__bf16)v1.w;
        }

        const float* xls = xl + (size_t)s * 256;
        const float* xrd = xr + (size_t)d * 256;

        float hsum[4] = {0.0f, 0.0f, 0.0f, 0.0f};
#pragma unroll
        for (int g = 0; g < 8; g++) {       /* 32-c block; head = g>>1 */
            f32x16 acc;
#pragma unroll
            for (int j = 0; j < 16; j++) acc[j] = 0.0f;
#pragma unroll
            for (int ks = 0; ks < 4; ks++) {
                bf16x8 wfr = *reinterpret_cast<const bf16x8*>(
                    &fb[(((g * 4 + ks) * 64) + lane) * 8]);
                acc = __builtin_amdgcn_mfma_f32_32x32x16_bf16(wfr, af[ks], acc, 0, 0, 0);
            }
            int cb0 = g * 32 + 4 * half;
            float hs = 0.0f;
#pragma unroll
            for (int q = 0; q < 4; q++) {   /* c chunk: cb0 + 8q .. +4 */
                int cb = cb0 + 8 * q;
                float4 xa = *reinterpret_cast<const float4*>(xls + cb);
                float4 xb = *reinterpret_cast<const float4*>(xrd + cb);
                float4 at = *reinterpret_cast<const float4*>(att + cb);
                const float* ap = reinterpret_cast<const float*>(&xa);
                const float* bp = reinterpret_cast<const float*>(&xb);
                const float* tp = reinterpret_cast<const float*>(&at);
#pragma unroll
                for (int j = 0; j < 4; j++) {
                    float v = acc[q * 4 + j] + ap[j] + bp[j];
                    v = (v >= 0.0f) ? v : NEG_SLOPE * v;
                    hs = fmaf(v, tp[j], hs);
                }
            }
            hsum[g >> 1] += hs;
        }
#pragma unroll
        for (int hh = 0; hh < 4; hh++) hsum[hh] += __shfl_xor(hsum[hh], 32, 64);
        if (half == 0 && e < NE_TOT) {
            reinterpret_cast<float4*>(logits)[e] =
                make_float4(hsum[0], hsum[1], hsum[2], hsum[3]);
        }
    }
}

/* one wave per node: online segment softmax + weighted sum + SiLU + LayerNorm */
__global__ void k_aggregate(const int* __restrict__ ei,
                            const int* __restrict__ row_ptr,
                            const int* __restrict__ eids,
                            const float* __restrict__ logits,
                            const float* __restrict__ xl,
                            const float* __restrict__ bias,
                            const float* __restrict__ gamma,
                            const float* __restrict__ beta,
                            float* __restrict__ hout,
                            float* __restrict__ alpha_out) {
    int node = (blockIdx.x << 2) + (threadIdx.x >> 6);
    int lane = threadIdx.x & 63;
    int h = lane >> 4;
    int b = row_ptr[node], en = row_ptr[node + 1];

    /* online max + denom in one pass */
    float mh = -INFINITY, den = 0.0f;
    for (int i = b; i < en; i++) {
        int e = eids[i];
        float l = logits[e * 4 + h];
        if (l > mh) {
            den = den * __expf(mh - l) + 1.0f;
            mh = l;
        } else {
            den += __expf(l - mh);
        }
    }
    float rden = 1.0f / den;

    const float4* xl4p = reinterpret_cast<const float4*>(xl);
    float4 acc; acc.x = acc.y = acc.z = acc.w = 0.0f;
    for (int i = b; i < en; i++) {
        int e = eids[i];
        float al = __expf(logits[e * 4 + h] - mh) * rden;
        if ((lane & 15) == 0) alpha_out[e * 4 + h] = al;
        int s = (e < N_EDGES) ? ei[e] : (e - N_EDGES);
        float4 xv = xl4p[s * 64 + lane];
        acc.x = fmaf(al, xv.x, acc.x);
        acc.y = fmaf(al, xv.y, acc.y);
        acc.z = fmaf(al, xv.z, acc.z);
        acc.w = fmaf(al, xv.w, acc.w);
    }

    const float4 b4 = reinterpret_cast<const float4*>(bias)[lane];
    float4 hv;
    hv.x = acc.x + b4.x; hv.y = acc.y + b4.y;
    hv.z = acc.z + b4.z; hv.w = acc.w + b4.w;
    /* SiLU */
    hv.x = hv.x / (1.0f + __expf(-hv.x));
    hv.y = hv.y / (1.0f + __expf(-hv.y));
    hv.z = hv.z / (1.0f + __expf(-hv.z));
    hv.w = hv.w / (1.0f + __expf(-hv.w));
    /* LayerNorm over 256 dims spread across 64 lanes x 4 */
    float s1 = hv.x + hv.y + hv.z + hv.w;
    float s2 = hv.x * hv.x + hv.y * hv.y + hv.z * hv.z + hv.w * hv.w;
#pragma unroll
    for (int off = 1; off < 64; off <<= 1) {
        s1 += __shfl_xor(s1, off, 64);
        s2 += __shfl_xor(s2, off, 64);
    }
    float mu = s1 * (1.0f / 256.0f);
    float var = s2 * (1.0f / 256.0f) - mu * mu;
    float rs = rsqrtf(var + LN_EPS);
    const float4 g4 = reinterpret_cast<const float4*>(gamma)[lane];
    const float4 be4 = reinterpret_cast<const float4*>(beta)[lane];
    float4 o;
    o.x = (hv.x - mu) * rs * g4.x + be4.x;
    o.y = (hv.y - mu) * rs * g4.y + be4.y;
    o.z = (hv.z - mu) * rs * g4.z + be4.z;
    o.w = (hv.w - mu) * rs * g4.w + be4.w;
    reinterpret_cast<float4*>(hout)[node * 64 + lane] = o;
}

extern "C" void kernel_launch(void* const* d_in, const int* in_sizes, int n_in,
                              void* d_out, int out_size, void* d_ws, size_t ws_size,
                              hipStream_t stream) {
    (void)in_sizes; (void)n_in; (void)out_size; (void)ws_size;
    const float* x         = (const float*)d_in[0];
    const int*   ei        = (const int*)d_in[1];
    const float* edge_attr = (const float*)d_in[2];
    const float* Wl        = (const float*)d_in[3];
    const float* bl        = (const float*)d_in[4];
    const float* Wr        = (const float*)d_in[5];
    const float* br        = (const float*)d_in[6];
    const float* We        = (const float*)d_in[7];
    const float* att       = (const float*)d_in[8];
    const float* bias      = (const float*)d_in[9];
    const float* gamma     = (const float*)d_in[10];
    const float* beta      = (const float*)d_in[11];

    char* ws = (char*)d_ws;
    int*   cnt     = (int*)(ws + OFF_CNT);
    int*   fill    = (int*)(ws + OFF_FILL);
    int*   row_ptr = (int*)(ws + OFF_ROWPTR);
    int*   eids    = (int*)(ws + OFF_EIDS);
    float* lattr   = (float*)(ws + OFF_LATTR);
    float* xl      = (float*)(ws + OFF_XL);
    float* xr      = (float*)(ws + OFF_XR);
    float* logits  = (float*)(ws + OFF_LOG);

    float* hout      = (float*)d_out;
    float* alpha_out = (float*)d_out + N_NODES * 256;

    hipMemsetAsync(ws + OFF_CNT, 0, 2 * N_NODES * sizeof(int), stream);

    k_count<<<(N_EDGES + 255) / 256, 256, 0, stream>>>(ei, cnt);
    k_scan<<<1, 256, 0, stream>>>(cnt, row_ptr);
    k_fill<<<(NE_TOT + 255) / 256, 256, 0, stream>>>(ei, row_ptr, fill, eids);
    k_loop_attr<<<N_NODES / 4, 256, 0, stream>>>(edge_attr, row_ptr, eids, cnt, lattr);
    k_gemm_xlxr<<<N_NODES / 8, 256, 0, stream>>>(x, Wl, bl, Wr, br, xl, xr);
    k_logits_mfma<<<1290, 256, 0, stream>>>(ei, edge_attr, lattr, xl, xr, We, att, logits);
    k_aggregate<<<N_NODES / 4, 256, 0, stream>>>(ei, row_ptr, eids, logits, xl,
                                                 bias, gamma, beta, hout, alpha_out);
}